// Round 21
// baseline (30.865 us; speedup 1.0000x reference)
//
#include <hip/hip_runtime.h>

// DivEncLayer via MFMA — r17 staging (best, 27.7us) + MERGED-HALF finish
// (3 shfl / 1 epilogue / 1 write per iter, was 6/2/2) + tail DEFERRED one
// iteration (carried in registers; overlaps next panel's MFMA+ELU).
// Per (b,q): h = elu(x[b,q*8:+8]@W1[q] + b1[q]); LN(h); out = h@W2[q]+b2[q].
// B=16384, Q=128, S=8, U=32.
//
// Merged finish (bit-identical arithmetic): output row b0+ln needs
// partial(half0,lane u) + partial(half1,lane u) of its tile (A for ln<32,
// B for ln>=32). Each lane KEEPS its own tile's partial and SENDS the other
// tile's partial: send = half? A : B; tot = (half? B : A) + shfl_xor(send,32).
// One epilogue per lane, one lout write at row b0+ln.
//
// v_mfma_f32_32x32x16_bf16 mapping (validated r2-r11):
//   A: lane l, reg j -> A[l&31][j+8*(l>>5)]  B: lane l, reg j -> B[j+8*(l>>5)][l&31]
//   D: lane l, reg r -> row u=(r&3)+8*(r>>2)+4*(l>>5), col b=l&31
// Packed A-frag: lanes<32 = bf16(W1^T) (k<8), lanes>=32 = bf16(W1-hi) (k>=8).
// D = (whi+wlo)*xhi + b1 (C-in fp32). LN+Dense2 folded:
//   out = rsqrt(var+eps)*(dot(e,g2) - mu*G) + C.
// Staging: r17's 3-deep ring, loads 2 iters ahead, lgkmcnt-only barriers
// (global loads in flight across barriers). Block = 4 waves = q-tile;
// 8 iters x 64 rows = 512-row band; grid (32,32). lout gather, float4 stores.

typedef __attribute__((ext_vector_type(8))) short short8;    // 8 bf16
typedef __attribute__((ext_vector_type(16))) float f32x16;

#define XS_STRIDE 40   // shorts per staged row (80 B): b128-aligned, 0-conflict

__device__ __forceinline__ short fbits(__bf16 b) { return __builtin_bit_cast(short, b); }

__device__ __forceinline__ float elu1(float v) {
    return v > 0.f ? v : __expf(v) - 1.f;
}

__device__ __forceinline__ short4 cvt4(float4 v) {
    short4 r;
    r.x = fbits((__bf16)v.x); r.y = fbits((__bf16)v.y);
    r.z = fbits((__bf16)v.z); r.w = fbits((__bf16)v.w);
    return r;
}

// barrier WITHOUT vmcnt drain: DS visibility only; global loads stay in flight
__device__ __forceinline__ void barrier_ds_only() {
    asm volatile("s_waitcnt lgkmcnt(0)" ::: "memory");
    __builtin_amdgcn_s_barrier();
}

__global__ __launch_bounds__(256, 4) void divenc_mfma(
    const float* __restrict__ x,      // (16384, 1024)
    const float* __restrict__ W1,     // (128, 8, 32)
    const float* __restrict__ b1,     // (128, 32)
    const float* __restrict__ gamma,  // (128, 32)
    const float* __restrict__ beta,   // (128, 32)
    const float* __restrict__ W2,     // (128, 32)
    const float* __restrict__ b2,     // (128,)
    float* __restrict__ out)          // (16384, 128)
{
    __shared__ short xs[3][64 * XS_STRIDE];   // 3-deep staged bf16 panels (15 KB)
    __shared__ float lout[512 * 5];           // results, padded stride 5 (10 KB)

    const int tid  = threadIdx.x;
    const int w    = tid >> 6;
    const int ln   = tid & 63;
    const int u    = ln & 31;
    const int half = ln >> 5;
    const int qt   = blockIdx.y;      // 0..31
    const int q    = qt * 4 + w;
    const int bx   = blockIdx.x;      // 0..31; band = rows bx*512..+511
    const int band = bx * 512;

    // staging role: 8 threads cover one 128B row; thread t does rows t>>3, +32
    const int srow0 = tid >> 3;
    const int srow1 = srow0 + 32;
    const int schk  = tid & 7;
    const float* xpan = x + qt * 32 + schk * 4;

    // ---- A-frag: lanes<32 = whi (k=0..7), lanes>=32 = wlo (k=8..15) ----
    short8 wfrag;
    #pragma unroll
    for (int j = 0; j < 8; ++j) {
        float f  = W1[q * 256 + j * 32 + u];
        __bf16 h = (__bf16)f;
        wfrag[j] = half ? fbits((__bf16)(f - (float)h)) : fbits(h);
    }

    // ---- params: biasr (MFMA C-in) + g2r in regs, vector loads ----
    f32x16 biasr, g2r;
    float G, C;
    {
        float gs = 0.f, cs = 0.f;
        #pragma unroll
        for (int c = 0; c < 4; ++c) {
            const int ub = q * 32 + 4 * half + 8 * c;
            float4 b1v = *(const float4*)&b1[ub];
            float4 gav = *(const float4*)&gamma[ub];
            float4 w2v = *(const float4*)&W2[ub];
            float4 bev = *(const float4*)&beta[ub];
            #pragma unroll
            for (int j = 0; j < 4; ++j) {
                float g2 = ((const float*)&gav)[j] * ((const float*)&w2v)[j];
                biasr[4 * c + j] = ((const float*)&b1v)[j];
                g2r[4 * c + j]   = g2;
                gs += g2;
                cs += ((const float*)&bev)[j] * ((const float*)&w2v)[j];
            }
        }
        gs += __shfl_xor(gs, 32);   // halves hold complementary u-sets
        cs += __shfl_xor(cs, 32);
        G = gs;
        C = cs + b2[q];
    }

    // ---- prologue: stage panel 0; issue panel 1's loads (stay in flight) ----
    {
        float4 g0 = *(const float4*)(xpan + (size_t)(band + srow0) * 1024);
        float4 g1 = *(const float4*)(xpan + (size_t)(band + srow1) * 1024);
        *(short4*)&xs[0][srow0 * XS_STRIDE + schk * 4] = cvt4(g0);
        *(short4*)&xs[0][srow1 * XS_STRIDE + schk * 4] = cvt4(g1);
    }
    float4 p0 = *(const float4*)(xpan + (size_t)(band + 64 + srow0) * 1024);
    float4 p1 = *(const float4*)(xpan + (size_t)(band + 64 + srow1) * 1024);
    barrier_ds_only();

    // deferred-tail registers (prev iter's merged partials)
    float dKs = 0.f, dKq = 0.f, dKd = 0.f;   // keep (own tile)
    float dSs = 0.f, dSq = 0.f, dSd = 0.f;   // send (other tile)

    #pragma unroll 1
    for (int it = 0; it < 8; ++it) {
        const int cur = it % 3;
        const int nxt = (it + 1) % 3;
        const int b0  = it * 64;        // row offset within band

        // issue loads for panel it+2 (2 iterations ahead; stay in flight)
        float4 f0, f1;
        if (it < 6) {
            f0 = *(const float4*)(xpan + (size_t)(band + b0 + 128 + srow0) * 1024);
            f1 = *(const float4*)(xpan + (size_t)(band + b0 + 128 + srow1) * 1024);
        }

        // ---- compute on panel cur ----
        short8 xa = *(const short8*)&xs[cur][u * XS_STRIDE + w * 8];
        short8 xb = *(const short8*)&xs[cur][(u + 32) * XS_STRIDE + w * 8];

        f32x16 accA = __builtin_amdgcn_mfma_f32_32x32x16_bf16(wfrag, xa, biasr, 0, 0, 0);
        f32x16 accB = __builtin_amdgcn_mfma_f32_32x32x16_bf16(wfrag, xb, biasr, 0, 0, 0);

        // ---- deferred finish of PREVIOUS iter (independent of panels):
        //      3 shfl + 1 epilogue + 1 write; overlaps this iter's MFMA/ELU ----
        if (it > 0) {
            float ts = dKs + __shfl_xor(dSs, 32);
            float tq = dKq + __shfl_xor(dSq, 32);
            float td = dKd + __shfl_xor(dSd, 32);
            float mu  = ts * 0.03125f;
            float var = fmaf(-mu, mu, tq * 0.03125f);
            float inv = rsqrtf(var + 1e-3f);
            float res = fmaf(inv, fmaf(-mu, G, td), C);
            lout[(b0 - 64 + ln) * 5 + w] = res;   // row (it-1)*64 + ln
        }

        // ---- current partials (stop before shfl) ----
        float sA = 0.f, qA = 0.f, dA = 0.f;
        float sB = 0.f, qB = 0.f, dB = 0.f;
        #pragma unroll
        for (int r = 0; r < 16; ++r) {
            float eA = elu1(accA[r]);
            float eB = elu1(accB[r]);
            sA += eA;                    sB += eB;
            qA = fmaf(eA, eA, qA);       qB = fmaf(eB, eB, qB);
            dA = fmaf(eA, g2r[r], dA);   dB = fmaf(eB, g2r[r], dB);
        }
        // keep own tile (A for half0, B for half1); send the other
        float nKs = half ? sB : sA, nSs = half ? sA : sB;
        float nKq = half ? qB : qA, nSq = half ? qA : qB;
        float nKd = half ? dB : dA, nSd = half ? dA : dB;

        // ---- write panel it+1 from pending regs (vmcnt counted, not drained) ----
        if (it < 7) {
            *(short4*)&xs[nxt][srow0 * XS_STRIDE + schk * 4] = cvt4(p0);
            *(short4*)&xs[nxt][srow1 * XS_STRIDE + schk * 4] = cvt4(p1);
            barrier_ds_only();   // DS visibility only; vmcnt NOT drained
        }

        dKs = nKs; dKq = nKq; dKd = nKd;
        dSs = nSs; dSq = nSq; dSd = nSd;
        p0 = f0;
        p1 = f1;
    }

    // ---- final deferred finish (iter 7's partials) ----
    {
        float ts = dKs + __shfl_xor(dSs, 32);
        float tq = dKq + __shfl_xor(dSq, 32);
        float td = dKd + __shfl_xor(dSd, 32);
        float mu  = ts * 0.03125f;
        float var = fmaf(-mu, mu, tq * 0.03125f);
        float inv = rsqrtf(var + 1e-3f);
        float res = fmaf(inv, fmaf(-mu, G, td), C);
        lout[(448 + ln) * 5 + w] = res;   // row 7*64 + ln
    }

    __syncthreads();   // full drain before the gather

    // ---- gather/store: 512 rows, 2 per thread, float4 each (write-exact) ----
    {
        const int r0 = tid;
        const int r1 = tid + 256;
        float4 o0, o1;
        o0.x = lout[r0 * 5 + 0]; o0.y = lout[r0 * 5 + 1];
        o0.z = lout[r0 * 5 + 2]; o0.w = lout[r0 * 5 + 3];
        o1.x = lout[r1 * 5 + 0]; o1.y = lout[r1 * 5 + 1];
        o1.z = lout[r1 * 5 + 2]; o1.w = lout[r1 * 5 + 3];
        *(float4*)(out + (size_t)(band + r0) * 128 + qt * 4) = o0;
        *(float4*)(out + (size_t)(band + r1) * 128 + qt * 4) = o1;
    }
}

extern "C" void kernel_launch(void* const* d_in, const int* in_sizes, int n_in,
                              void* d_out, int out_size, void* d_ws, size_t ws_size,
                              hipStream_t stream) {
    const float* x     = (const float*)d_in[0];
    const float* W1    = (const float*)d_in[1];
    const float* b1    = (const float*)d_in[2];
    const float* gamma = (const float*)d_in[3];
    const float* beta  = (const float*)d_in[4];
    const float* W2    = (const float*)d_in[5];
    const float* b2    = (const float*)d_in[6];
    float* out = (float*)d_out;

    dim3 grid(32, 32);   // (512-row bands, q-tiles of 4)
    divenc_mfma<<<grid, 256, 0, stream>>>(x, W1, b1, gamma, beta, W2, b2, out);
}